// Round 1
// baseline (478.580 us; speedup 1.0000x reference)
//
#include <hip/hip_runtime.h>
#include <math.h>

static constexpr int B = 2, H = 1024, W = 1024, CIN = 18;
static constexpr int TILE = 16;           // 16x16 output pixels per block
static constexpr int HALO = 3;            // max dilation
static constexpr int SW   = TILE + 2*HALO;       // 22
static constexpr int ROWW = SW * CIN;            // 396 floats per staged row
static constexpr int NCELL = 16;                 // cells per axis

__device__ __forceinline__ int cell_of(const int* __restrict__ loc, int x) {
    int id = 0;
#pragma unroll
    for (int i = 1; i < NCELL; ++i) id = (loc[i] <= x) ? i : id;
    return id;
}

__global__ __launch_bounds__(256)
void conv_main(const float* __restrict__ in,
               const int* __restrict__ row_loc, const int* __restrict__ col_loc,
               const float* __restrict__ w1, const float* __restrict__ b1,
               const float* __restrict__ w2, const float* __restrict__ b2,
               const float* __restrict__ w3, const float* __restrict__ b3,
               const float* __restrict__ wb1, const float* __restrict__ bb1,
               const float* __restrict__ wb2, const float* __restrict__ bb2,
               float* __restrict__ out, float* __restrict__ sums)
{
    __shared__ float s_in[SW * ROWW];     // 22*396 floats = 34848 B
    __shared__ float s_red[4][19];

    const int tid = threadIdx.x;
    const int bx  = blockIdx.x;
    const int b   = bx >> 12;                 // 4096 tiles per batch image
    const int rem = bx & 4095;
    const int h0  = (rem >> 6) * TILE;
    const int w0  = (rem & 63) * TILE;

    // ---- stage input tile with halo ----
    const int gh0 = h0 - HALO, gw0 = w0 - HALO;
    const bool interior = (gh0 >= 0) && (h0 + TILE + HALO <= H) &&
                          (gw0 >= 0) && (w0 + TILE + HALO <= W);
    if (interior) {
        const float2* src = (const float2*)(in + ((size_t)((size_t)b*H + gh0)*W + gw0)*CIN);
        const int rowp2 = (W*CIN) >> 1;       // float2 pitch of a global row
        float2* dst = (float2*)s_in;
        for (int t = tid; t < SW * (ROWW>>1); t += 256) {
            int r = t / (ROWW>>1), c2 = t - r*(ROWW>>1);
            dst[r*(ROWW>>1) + c2] = src[(size_t)r*rowp2 + c2];
        }
    } else {
        for (int t = tid; t < SW * ROWW; t += 256) {
            int r = t / ROWW, rr = t - r*ROWW;
            int col = rr / CIN, ch = rr - col*CIN;
            int gh = gh0 + r, gw = gw0 + col;
            float v = 0.f;
            if (gh >= 0 && gh < H && gw >= 0 && gw < W)
                v = in[((size_t)((size_t)b*H + gh)*W + gw)*CIN + ch];
            s_in[t] = v;
        }
    }
    __syncthreads();

    const int ty = tid >> 4, tx = tid & 15;
    const int h = h0 + ty, w = w0 + tx;

    // ---- three dilated 3x3 convs (18 -> 6 each), fp32 ----
    float c[18];
#pragma unroll
    for (int k = 0; k < 6; ++k) { c[k] = b1[k]; c[6+k] = b2[k]; c[12+k] = b3[k]; }

    const float* wp0 = w1; const float* wp1 = w2; const float* wp2 = w3;
#pragma unroll
    for (int cv = 0; cv < 3; ++cv) {
        const int d = cv + 1;
        const float* wq = (cv == 0) ? wp0 : (cv == 1) ? wp1 : wp2;
        for (int ky = 0; ky < 3; ++ky) {
            for (int kx = 0; kx < 3; ++kx) {
                const int ry = ty + HALO + (ky-1)*d;
                const int rx = tx + HALO + (kx-1)*d;
                const float* ip = &s_in[(ry*SW + rx)*CIN];
                float xin[18];
#pragma unroll
                for (int ci = 0; ci < 18; ci += 2) {
                    float2 v = *(const float2*)&ip[ci];
                    xin[ci] = v.x; xin[ci+1] = v.y;
                }
                const float* wt = wq + (ky*3 + kx)*CIN*6;
#pragma unroll
                for (int ci = 0; ci < 18; ++ci)
#pragma unroll
                    for (int co = 0; co < 6; ++co)
                        c[cv*6 + co] += xin[ci] * wt[ci*6 + co];
            }
        }
    }
#pragma unroll
    for (int k = 0; k < 18; ++k) c[k] = fmaxf(c[k], 0.f);

    // ---- write c to output channels 18..35 ----
    float* op = out + ((size_t)((size_t)b*H + h)*W + w)*37;
#pragma unroll
    for (int k = 0; k < 18; ++k) op[18 + k] = c[k];

    // ---- 1x1 convs ----
    float v1[18];
#pragma unroll
    for (int k = 0; k < 18; ++k) v1[k] = bb1[k];
#pragma unroll
    for (int ci = 0; ci < 18; ++ci)
#pragma unroll
        for (int co = 0; co < 18; ++co)
            v1[co] += c[ci] * wb1[ci*18 + co];
#pragma unroll
    for (int k = 0; k < 18; ++k) v1[k] = fmaxf(v1[k], 0.f);

    float v2 = bb2[0];
#pragma unroll
    for (int ci = 0; ci < 18; ++ci) v2 += c[ci] * wb2[ci];

    // ---- per-cell sums ----
    const int rid0 = cell_of(row_loc, h0),  rid1 = cell_of(row_loc, h0 + TILE - 1);
    const int cid0 = cell_of(col_loc, w0),  cid1 = cell_of(col_loc, w0 + TILE - 1);
    if (rid0 == rid1 && cid0 == cid1) {
        // whole tile in one cell (always true for the 64-aligned grid)
#pragma unroll
        for (int k = 0; k < 18; ++k) {
            float s = v1[k];
            for (int off = 32; off >= 1; off >>= 1) s += __shfl_xor(s, off);
            if ((tid & 63) == 0) s_red[tid >> 6][k] = s;
        }
        {
            float s = v2;
            for (int off = 32; off >= 1; off >>= 1) s += __shfl_xor(s, off);
            if ((tid & 63) == 0) s_red[tid >> 6][18] = s;
        }
        __syncthreads();
        if (tid < 19) {
            float s = s_red[0][tid] + s_red[1][tid] + s_red[2][tid] + s_red[3][tid];
            const int cell = b*256 + rid0*16 + cid0;
            atomicAdd(&sums[cell*19 + tid], s);
        }
    } else {
        const int rid = cell_of(row_loc, h), cid = cell_of(col_loc, w);
        const int cell = b*256 + rid*16 + cid;
#pragma unroll
        for (int k = 0; k < 18; ++k) atomicAdd(&sums[cell*19 + k], v1[k]);
        atomicAdd(&sums[cell*19 + 18], v2);
    }
}

__global__ __launch_bounds__(256)
void finalize(const int* __restrict__ row_loc, const int* __restrict__ col_loc,
              const float* __restrict__ sums,
              float* __restrict__ pooled1, float* __restrict__ pooled2,
              int* __restrict__ row_ids, int* __restrict__ col_ids)
{
    __shared__ int rcnt[NCELL], ccnt[NCELL];
    const int tid = threadIdx.x;
    if (tid < NCELL) { rcnt[tid] = 0; ccnt[tid] = 0; }
    __syncthreads();
    for (int h = tid; h < H; h += 256) {
        int r = cell_of(row_loc, h); row_ids[h] = r; atomicAdd(&rcnt[r], 1);
    }
    for (int w = tid; w < W; w += 256) {
        int cc = cell_of(col_loc, w); col_ids[w] = cc; atomicAdd(&ccnt[cc], 1);
    }
    __syncthreads();
    for (int t = tid; t < B*256*18; t += 256) {
        int cell = t / 18, ch = t - cell*18;
        int rid = (cell >> 4) & 15, cid = cell & 15;
        int cnt = rcnt[rid] * ccnt[cid];
        pooled1[t] = (cnt > 0) ? sums[cell*19 + ch] / (float)cnt : 0.f;
    }
    for (int t = tid; t < B*256; t += 256) {
        int rid = (t >> 4) & 15, cid = t & 15;
        int cnt = rcnt[rid] * ccnt[cid];
        float v = (cnt > 0) ? sums[t*19 + 18] / (float)cnt : 0.f;
        pooled2[t] = 1.f / (1.f + expf(-v));
    }
}

__global__ __launch_bounds__(256)
void broadcast(const float* __restrict__ pooled1, const float* __restrict__ pooled2,
               const int* __restrict__ row_ids, const int* __restrict__ col_ids,
               float* __restrict__ out, float* __restrict__ out2)
{
    const int pix = blockIdx.x * 256 + threadIdx.x;      // < B*H*W
    const int b  = pix >> 20;
    const int hw = pix & ((1 << 20) - 1);
    const int h  = hw >> 10, w = hw & 1023;
    const int cell = b*256 + row_ids[h]*16 + col_ids[w];
    const float2* p1 = (const float2*)(pooled1 + cell*18);
    const float p2 = pooled2[cell];
    float* op = out + (size_t)pix * 37;
#pragma unroll
    for (int k = 0; k < 9; ++k) { float2 v = p1[k]; op[2*k] = v.x; op[2*k + 1] = v.y; }
    op[36] = p2;
    out2[pix] = p2;
}

extern "C" void kernel_launch(void* const* d_in, const int* in_sizes, int n_in,
                              void* d_out, int out_size, void* d_ws, size_t ws_size,
                              hipStream_t stream)
{
    (void)in_sizes; (void)n_in; (void)out_size; (void)ws_size;
    const float* in      = (const float*)d_in[0];
    const int*   row_loc = (const int*)d_in[1];
    const int*   col_loc = (const int*)d_in[2];
    const float *w1 = (const float*)d_in[3],  *b1  = (const float*)d_in[4];
    const float *w2 = (const float*)d_in[5],  *b2  = (const float*)d_in[6];
    const float *w3 = (const float*)d_in[7],  *b3  = (const float*)d_in[8];
    const float *wb1= (const float*)d_in[9],  *bb1 = (const float*)d_in[10];
    const float *wb2= (const float*)d_in[11], *bb2 = (const float*)d_in[12];

    float* out  = (float*)d_out;
    float* out2 = out + (size_t)B*H*W*37;

    float* sums    = (float*)d_ws;            // B*256*19 floats
    float* pooled1 = sums + B*256*19;         // B*256*18
    float* pooled2 = pooled1 + B*256*18;      // B*256
    int*   row_ids = (int*)(pooled2 + B*256); // H
    int*   col_ids = row_ids + H;             // W

    hipMemsetAsync(sums, 0, (size_t)B*256*19*sizeof(float), stream);

    conv_main<<<dim3(B*(H/TILE)*(W/TILE)), dim3(256), 0, stream>>>(
        in, row_loc, col_loc, w1, b1, w2, b2, w3, b3, wb1, bb1, wb2, bb2,
        out, sums);

    finalize<<<dim3(1), dim3(256), 0, stream>>>(
        row_loc, col_loc, sums, pooled1, pooled2, row_ids, col_ids);

    broadcast<<<dim3((B*H*W)/256), dim3(256), 0, stream>>>(
        pooled1, pooled2, row_ids, col_ids, out, out2);
}